// Round 6
// baseline (28.654 us; speedup 1.0000x reference)
//
#include <hip/hip_runtime.h>
#include <hip/hip_bf16.h>

// Co-attention collapses: softmax over a size-1 axis == 1.0 exactly, so
//   out[b, 0:10]  = sum_{l<12}  x1[b, l, :]
//   out[b, 10:20] = sum_{l<100} C [b, l, :]
// Pure memory-bound column-sum. B=16384, LC=100, LS=12, D=10.
//
// R5: fix compile error — __builtin_nontemporal_load needs a native
// clang vector type, not HIP's float2 class. Use ext_vector_type(2).
// Structure = R3 best (4-way row split, float2 loads, shfl_xor combine,
// 1280 blocks = 5/CU, 20 waves/CU) + non-temporal loads on the
// read-once stream.

#define BATCHES 16384

typedef float f2v __attribute__((ext_vector_type(2)));

__global__ __launch_bounds__(256) void coattention_sum_kernel(
    const float* __restrict__ C,
    const float* __restrict__ x1,
    float* __restrict__ out)
{
    const int t = threadIdx.x;
    const int lane = t & 63;
    const int q = lane >> 4;                 // quarter 0..3
    const int wave = t >> 6;                 // 0..3
    const int u = blockIdx.x * 64 + wave * 16 + (lane & 15);
    const int b = u / 5;
    const int p = u - b * 5;                 // column-pair 0..4

    // f2v views: C batch = 500 float2 (100 rows x 5), x1 batch = 60 (12 x 5)
    const f2v* __restrict__ cp =
        reinterpret_cast<const f2v*>(C) + (size_t)b * 500 + q * 125 + p;
    const f2v* __restrict__ xp =
        reinterpret_cast<const f2v*>(x1) + (size_t)b * 60 + q * 15 + p;

    float sx = 0.f, sy = 0.f;
#pragma unroll
    for (int l = 0; l < 3; ++l) {
        f2v v = __builtin_nontemporal_load(&xp[l * 5]);
        sx += v.x; sy += v.y;
    }

    float cx = 0.f, cy = 0.f;
#pragma unroll
    for (int l = 0; l < 25; ++l) {
        f2v v = __builtin_nontemporal_load(&cp[l * 5]);
        cx += v.x; cy += v.y;
    }

    // combine quarters: xor 16 (q0<->q1, q2<->q3), then xor 32
    sx += __shfl_xor(sx, 16); sy += __shfl_xor(sy, 16);
    cx += __shfl_xor(cx, 16); cy += __shfl_xor(cy, 16);
    sx += __shfl_xor(sx, 32); sy += __shfl_xor(sy, 32);
    cx += __shfl_xor(cx, 32); cy += __shfl_xor(cy, 32);

    if (q == 0) {
        float2* o = reinterpret_cast<float2*>(out) + (size_t)b * 10;
        o[p]     = make_float2(sx, sy);   // sfinal cols 2p, 2p+1
        o[5 + p] = make_float2(cx, cy);   // cfinal cols 2p, 2p+1
    }
}

extern "C" void kernel_launch(void* const* d_in, const int* in_sizes, int n_in,
                              void* d_out, int out_size, void* d_ws, size_t ws_size,
                              hipStream_t stream) {
    const float* C  = (const float*)d_in[0];   // (B,100,10)
    const float* x1 = (const float*)d_in[1];   // (B,12,10)
    float* out = (float*)d_out;                // (B,1,20)

    const int units = BATCHES * 5;             // 81920 (b, column-pair)
    const int grid = units / 64;               // 1280 blocks = 5/CU exactly
    coattention_sum_kernel<<<grid, 256, 0, stream>>>(C, x1, out);
}

// Round 7
// 20.855 us; speedup vs baseline: 1.3740x; 1.3740x over previous
//
#include <hip/hip_runtime.h>
#include <hip/hip_bf16.h>

// Co-attention collapses: softmax over a size-1 axis == 1.0 exactly, so
//   out[b, 0:10]  = sum_{l<12}  x1[b, l, :]
//   out[b, 10:20] = sum_{l<100} C [b, l, :]
// Memory-bound column-sum. B=16384, LC=100, LS=12, D=10.
//
// R6 post-mortem: NT loads +10.8us == 73MB at HBM rate -> baseline reads
// are L3-resident, yet effective rate is only ~4.2 TB/s. Suspect:
// request fragmentation (wave-loads touch 16 scattered 40B segments).
// This round isolates it: Phase 1 stages 16 batches (70KB) to LDS with
// PERFECTLY CONTIGUOUS float4 wave loads (memcpy-grade); Phase 2 = R3's
// proven compute reading LDS, shfl_xor(1,2) combine over q (low bits).
// 320 thr: phase1 = 4480 float4 in 14 rounds; phase2 = 320 units
// (16 b x 5 p x 4 q) exactly. 70KB LDS -> 2 blocks/CU; grid 1024.

#define BATCHES 16384
#define NB 16   // batches per block

__global__ __launch_bounds__(320) void coattention_sum_kernel(
    const float4* __restrict__ C4,   // (B, 250) float4
    const float4* __restrict__ x14,  // (B, 30) float4
    float* __restrict__ out)         // (B, 20)
{
    __shared__ __align__(16) float4 lds4[NB * 250 + NB * 30];  // 4480 float4 = 70 KB

    const int t = threadIdx.x;  // 0..319

    // ---- Phase 1: contiguous global -> LDS copy (coalesced float4) ----
    const float4* __restrict__ Cg = C4 + (size_t)blockIdx.x * (NB * 250);  // 4000 f4
    const float4* __restrict__ Xg = x14 + (size_t)blockIdx.x * (NB * 30);  // 480 f4
#pragma unroll
    for (int k = 0; k < 12; ++k)          // 3840 of C
        lds4[k * 320 + t] = Cg[k * 320 + t];
    if (t < 160)                          // remaining 160 of C
        lds4[3840 + t] = Cg[3840 + t];
    lds4[4000 + t] = Xg[t];               // 320 of x1
    if (t < 160)                          // remaining 160 of x1
        lds4[4320 + t] = Xg[320 + t];
    __syncthreads();

    // ---- Phase 2: column-pair sums from LDS, quarter-split over q ----
    const int unit = t >> 2;             // 0..79
    const int q = t & 3;                 // row quarter
    const int b = unit / 5;              // local batch 0..15
    const int p = unit - b * 5;          // column-pair 0..4

    // float2 views: C batch = 500 f2 (100 rows x 5); x1 batch = 60 f2 (12 x 5)
    const float2* __restrict__ lbase = reinterpret_cast<const float2*>(lds4);
    const float2* __restrict__ lc = lbase + b * 500 + q * 125 + p;
    const float2* __restrict__ lx = lbase + 8000 + b * 60 + q * 15 + p;

    float cx = 0.f, cy = 0.f;
#pragma unroll
    for (int l = 0; l < 25; ++l) { float2 v = lc[l * 5]; cx += v.x; cy += v.y; }

    float sx = 0.f, sy = 0.f;
#pragma unroll
    for (int l = 0; l < 3; ++l)  { float2 v = lx[l * 5]; sx += v.x; sy += v.y; }

    // combine quarters: q lives in bits 0..1 of t -> shfl_xor 1 then 2
    cx += __shfl_xor(cx, 1); cy += __shfl_xor(cy, 1);
    sx += __shfl_xor(sx, 1); sy += __shfl_xor(sy, 1);
    cx += __shfl_xor(cx, 2); cy += __shfl_xor(cy, 2);
    sx += __shfl_xor(sx, 2); sy += __shfl_xor(sy, 2);

    if (q == 0) {
        float2* o = reinterpret_cast<float2*>(out)
                  + ((size_t)blockIdx.x * NB + b) * 10;
        o[p]     = make_float2(sx, sy);   // sfinal cols 2p, 2p+1
        o[5 + p] = make_float2(cx, cy);   // cfinal cols 2p, 2p+1
    }
}

extern "C" void kernel_launch(void* const* d_in, const int* in_sizes, int n_in,
                              void* d_out, int out_size, void* d_ws, size_t ws_size,
                              hipStream_t stream) {
    const float4* C4  = (const float4*)d_in[0];   // (B,100,10) = (B,250) float4
    const float4* x14 = (const float4*)d_in[1];   // (B,12,10)  = (B,30)  float4
    float* out = (float*)d_out;                   // (B,1,20)

    const int grid = BATCHES / NB;                // 1024 blocks
    coattention_sum_kernel<<<grid, 320, 0, stream>>>(C4, x14, out);
}

// Round 8
// 17.975 us; speedup vs baseline: 1.5941x; 1.1602x over previous
//
#include <hip/hip_runtime.h>
#include <hip/hip_bf16.h>

// Co-attention collapses: softmax over a size-1 axis == 1.0 exactly, so
//   out[b, 0:10]  = sum_{l<12}  x1[b, l, :]
//   out[b, 10:20] = sum_{l<100} C [b, l, :]
// Pure memory-bound column-sum. B=16384, LC=100, LS=12, D=10.
//
// FINAL (revert to R3 best = 17.84 us). Session evidence:
//   scalar 19.65 | f2 2-split 18.35 | f2 4-split 17.84 | f4+LDS-atomic
//   19.50 | NT (HBM-forced) 28.65 | LDS-staged contiguous 20.85.
// Load width, instr count, occupancy, balance, and span contiguity all
// nulled (<=1.5us). NT regression proves stream is cache-resident;
// staged-contiguous regression proves the read path (not the access
// pattern) caps at ~4.5 TB/s effective. Floor = 73 MB mandatory reads
// at read-path rate + fixed replay overhead. This structure is at it.
//
// Unit u = (b, p): batch b, column-pair p (row = 5 float2, p in 0..4).
// Wave: lane = q*16 + idx; quarter q sums C rows [25q,25q+25) and x1
// rows [3q,3q+3). shfl_xor 16 then 32 combines. Block = 256 thr = 64
// units. Grid = 81920/64 = 1280 = 5 blocks/CU exactly, 20 waves/CU.

#define BATCHES 16384

__global__ __launch_bounds__(256) void coattention_sum_kernel(
    const float* __restrict__ C,
    const float* __restrict__ x1,
    float* __restrict__ out)
{
    const int t = threadIdx.x;
    const int lane = t & 63;
    const int q = lane >> 4;                 // quarter 0..3
    const int wave = t >> 6;                 // 0..3
    const int u = blockIdx.x * 64 + wave * 16 + (lane & 15);
    const int b = u / 5;
    const int p = u - b * 5;                 // column-pair 0..4

    // float2 views: C batch = 500 float2 (100 rows x 5), x1 batch = 60 (12 x 5)
    const float2* __restrict__ cp =
        reinterpret_cast<const float2*>(C) + (size_t)b * 500 + q * 125 + p;
    const float2* __restrict__ xp =
        reinterpret_cast<const float2*>(x1) + (size_t)b * 60 + q * 15 + p;

    float sx = 0.f, sy = 0.f;
#pragma unroll
    for (int l = 0; l < 3; ++l)  { float2 v = xp[l * 5]; sx += v.x; sy += v.y; }

    float cx = 0.f, cy = 0.f;
#pragma unroll
    for (int l = 0; l < 25; ++l) { float2 v = cp[l * 5]; cx += v.x; cy += v.y; }

    // combine quarters: xor 16 (q0<->q1, q2<->q3), then xor 32
    sx += __shfl_xor(sx, 16); sy += __shfl_xor(sy, 16);
    cx += __shfl_xor(cx, 16); cy += __shfl_xor(cy, 16);
    sx += __shfl_xor(sx, 32); sy += __shfl_xor(sy, 32);
    cx += __shfl_xor(cx, 32); cy += __shfl_xor(cy, 32);

    if (q == 0) {
        float2* o = reinterpret_cast<float2*>(out) + (size_t)b * 10;
        o[p]     = make_float2(sx, sy);   // sfinal cols 2p, 2p+1
        o[5 + p] = make_float2(cx, cy);   // cfinal cols 2p, 2p+1
    }
}

extern "C" void kernel_launch(void* const* d_in, const int* in_sizes, int n_in,
                              void* d_out, int out_size, void* d_ws, size_t ws_size,
                              hipStream_t stream) {
    const float* C  = (const float*)d_in[0];   // (B,100,10)
    const float* x1 = (const float*)d_in[1];   // (B,12,10)
    float* out = (float*)d_out;                // (B,1,20)

    const int units = BATCHES * 5;             // 81920 (b, column-pair)
    const int grid = units / 64;               // 1280 blocks = 5/CU exactly
    coattention_sum_kernel<<<grid, 256, 0, stream>>>(C, x1, out);
}